// Round 14
// baseline (344.584 us; speedup 1.0000x reference)
//
#include <hip/hip_runtime.h>
#include <float.h>
#include <math.h>

typedef __bf16 bf16;
typedef __attribute__((ext_vector_type(8))) __bf16 bf16x8;
typedef __attribute__((ext_vector_type(4))) float f32x4;
typedef __attribute__((ext_vector_type(4))) int i32x4;
typedef long long i64;

#define MK 544  // Mg row stride (bf16); cols [0,515) real, rest zero

// Compiler-level memory fence: pins LDS op order across cross-lane
// producer->consumer edges (r13 lesson: per-thread alias analysis may
// otherwise hoist a ds_read above another lane's ds_write). Zero runtime cost.
#define LDS_FENCE() asm volatile("" ::: "memory")

// workspace byte offsets
#define WS_MG   0        // bf16[16*544]   = 17408 B
#define WS_CVEC 17408    // f32[16]        = 64 B
#define WS_W1F  17472    // i64[2*2*64]    = 2048 B   (fp8 conv1 frags, x16)
#define WS_W2F  19520    // i64[4*3*64]    = 6144 B   (fp8 conv2 frags, x16)

__device__ __forceinline__ f32x4 mfma16(bf16x8 a, bf16x8 b, f32x4 c) {
  return __builtin_amdgcn_mfma_f32_16x16x32_bf16(a, b, c, 0, 0, 0);
}
__device__ __forceinline__ f32x4 mfma8(i64 a, i64 b, f32x4 c) {
  return __builtin_amdgcn_mfma_f32_16x16x32_fp8_fp8(a, b, c, 0, 0, 0);
}

// ---------------------------------------------------------------------------
// Precompute (grid 35): blocks 0..33 build Mg[n][k] (bf16; k<515 real, rest 0)
// and cvec[n]; block 34 builds fp8 weight fragment tables (both scaled x16).
// ---------------------------------------------------------------------------
__global__ __launch_bounds__(256) void acek_pre(
    const float* __restrict__ led_feats, const float* __restrict__ led_pos,
    const float* __restrict__ q_w, const float* __restrict__ q_b,
    const float* __restrict__ k_w, const float* __restrict__ k_b,
    const float* __restrict__ c1w, const float* __restrict__ c2w,
    char* __restrict__ ws) {
  bf16* Mg = (bf16*)(ws + WS_MG);
  float* cvec = (float*)(ws + WS_CVEC);
  i64* W1F = (i64*)(ws + WS_W1F);
  i64* W2F = (i64*)(ws + WS_W2F);
  const int t = threadIdx.x;

  if (blockIdx.x == 34) {
    {  // conv1 fp8 frags: idx (ot*2+s)*64+lane; elem j <-> k1 = s*32+g*8+j
      int ot = t >> 7, s = (t >> 6) & 1, lane = t & 63;
      int g = lane >> 4, a15 = lane & 15;
      float v[8];
#pragma unroll
      for (int j = 0; j < 8; ++j) {
        int k1 = s * 32 + g * 8 + j;
        int dk = k1 >> 4, ic = k1 & 15;
        v[j] = (ic < 12 && dk < 3) ? 16.f * c1w[(ot * 16 + a15) * 36 + ic * 3 + dk] : 0.f;
      }
      int lo = __builtin_amdgcn_cvt_pk_fp8_f32(v[0], v[1], 0, false);
      lo = __builtin_amdgcn_cvt_pk_fp8_f32(v[2], v[3], lo, true);
      int hi = __builtin_amdgcn_cvt_pk_fp8_f32(v[4], v[5], 0, false);
      hi = __builtin_amdgcn_cvt_pk_fp8_f32(v[6], v[7], hi, true);
      W1F[t] = ((i64)(unsigned)lo) | (((i64)hi) << 32);
    }
    for (int r = 0; r < 3; ++r) {  // conv2 fp8 frags
      int fi = t + r * 256;
      int o = fi / 192, rem = fi - o * 192;
      int s = rem >> 6, lane = rem & 63;
      int g = lane >> 4, a15 = lane & 15;
      float v[8];
#pragma unroll
      for (int j = 0; j < 8; ++j)
        v[j] = 16.f * c2w[(o * 16 + a15) * 96 + (g * 8 + j) * 3 + s];
      int lo = __builtin_amdgcn_cvt_pk_fp8_f32(v[0], v[1], 0, false);
      lo = __builtin_amdgcn_cvt_pk_fp8_f32(v[2], v[3], lo, true);
      int hi = __builtin_amdgcn_cvt_pk_fp8_f32(v[4], v[5], 0, false);
      hi = __builtin_amdgcn_cvt_pk_fp8_f32(v[6], v[7], hi, true);
      W2F[fi] = ((i64)(unsigned)lo) | (((i64)hi) << 32);
    }
    return;
  }

  __shared__ float keys[16 * 64];
  for (int idx = t; idx < 16 * 64; idx += 256) {
    int n = idx >> 6, d = idx & 63;
    float acc = k_b[d];
#pragma unroll
    for (int j = 0; j < 8; ++j) acc += k_w[d * 11 + j] * led_feats[n * 8 + j];
#pragma unroll
    for (int j = 0; j < 3; ++j) acc += k_w[d * 11 + 8 + j] * led_pos[n * 3 + j];
    keys[idx] = acc;
  }
  __syncthreads();
  int e = blockIdx.x * 256 + t;
  if (e < 16 * MK) {
    int n = e / MK, k = e - n * MK;
    float v = 0.f;
    if (k < 515) {
#pragma unroll 4
      for (int d = 0; d < 64; ++d) v += q_w[d * 515 + k] * keys[n * 64 + d];
    }
    Mg[e] = (bf16)v;
  }
  if (blockIdx.x == 0 && t < 16) {
    float acc = 0.f;
    for (int d = 0; d < 64; ++d) acc += q_b[d] * keys[t * 64 + d];
    cvec[t] = acc;
  }
}

// ---------------------------------------------------------------------------
// Main: ONE WAVE = ONE BATCH, fully independent; ZERO barriers.
// r9 structure + full strip unroll + LDS_FENCE at every cross-lane LDS
// producer->consumer edge (conv1->conv2 ring, conv2->next-conv1 ring alias,
// staging->conv1, sagg, comb). The fences make the unroll safe: r13 showed
// compile-time ring offsets let per-thread alias analysis hoist ds_reads
// above other lanes' ds_writes.
// ---------------------------------------------------------------------------
__global__ __launch_bounds__(256, 4) void acek_main(
    const float* __restrict__ rss, const float* __restrict__ anchor,
    const float* __restrict__ ledf, const float* __restrict__ ledp,
    const int* __restrict__ fmask,
    const float* __restrict__ c1b, const float* __restrict__ c2b,
    const float* __restrict__ rw, const float* __restrict__ rb,
    const float* __restrict__ fw, const float* __restrict__ fb,
    const bf16* __restrict__ Mg, const float* __restrict__ cvec,
    const i64* __restrict__ W1F, const i64* __restrict__ W2F,
    float* __restrict__ out) {

  __shared__ __align__(16) unsigned char pool[4][9792];

  const int tid = threadIdx.x;
  const int lane = tid & 63;
  const int wv = tid >> 6;
  const int a15 = lane & 15;
  const int g = lane >> 4;
  const int b = blockIdx.x * 4 + wv;

  char* xw = (char*)pool[wv];                 // 515 rows x 16 B (fp8 x16)
  char* ring = (char*)pool[wv] + 8240;        // 48 rows x 32 B (h1 fp8)
  float* sagg = (float*)pool[wv];             // 96 f32, overlays dead xw
  float* comb = (float*)(pool[wv] + 8240);    // 128 f32, overlays dead ring

  // ---- fragment/bias loads ----
  i64 w1f[2][2];
#pragma unroll
  for (int ot = 0; ot < 2; ++ot)
#pragma unroll
    for (int s = 0; s < 2; ++s) w1f[ot][s] = W1F[(ot * 2 + s) * 64 + lane];
  i64 w2f[4][3];
#pragma unroll
  for (int o = 0; o < 4; ++o)
#pragma unroll
    for (int s = 0; s < 3; ++s) w2f[o][s] = W2F[(o * 3 + s) * 64 + lane];
  f32x4 b1v[2], b2s[4];
#pragma unroll
  for (int ot = 0; ot < 2; ++ot) b1v[ot] = *(const f32x4*)&c1b[ot * 16 + g * 4];
#pragma unroll
  for (int o = 0; o < 4; ++o) {
    f32x4 tmp = *(const f32x4*)&c2b[o * 16 + g * 4];
    b2s[o] = tmp * 16.f;  // conv2 fp8 weight scale folded into bias
  }

  // ---- zero pads (own wave's LDS only) ----
  for (int r = lane; r < 515; r += 64) *(int*)(xw + r * 16 + 12) = 0;  // cols 12-15
  if (lane < 12) {  // xw rows 0, 513, 514 (cols 0-15)
    int rr = (lane >> 2) == 0 ? 0 : ((lane >> 2) == 1 ? 513 : 514);
    *(int*)(xw + rr * 16 + (lane & 3) * 4) = 0;
  }
  if (lane < 4) *(i64*)(ring + lane * 8) = 0;  // ring slot 0 = h1 row 0 (zero pad)

  // ---- stage own batch: 24 coalesced f32x4 per lane -> fp8 (x16) LDS ----
  const float* xb = rss + (size_t)b * 6144;
  const f32x4* xb4 = (const f32x4*)xb;
#pragma unroll
  for (int i = 0; i < 24; ++i) {
    int f = lane + 64 * i;
    f32x4 v = xb4[f];
    int w = f / 3;
    int c = f - w * 3;  // {0,1,2}
    int pk = __builtin_amdgcn_cvt_pk_fp8_f32(16.f * v[0], 16.f * v[1], 0, false);
    pk = __builtin_amdgcn_cvt_pk_fp8_f32(16.f * v[2], 16.f * v[3], pk, true);
    *(int*)(xw + (w + 1) * 16 + c * 4) = pk;
  }
  LDS_FENCE();  // staging/pads -> conv1 reads (cross-lane)

  // ---- fused conv1 -> ring -> conv2, 16 strips of 32 outputs (FULL UNROLL,
  //      fence-pinned ring handoffs) ----
  const int icb = (g & 1) << 3;  // xw byte sub-block
  const int dk0 = g >> 1;
  const int dW[2] = {a15 + 1, a15 + 17};  // conv1-write d = row - 32pt
  const int dR0 = 2 * a15;                // conv2-read base d

  float tacc[4][4] = {{0.f, 0.f, 0.f, 0.f}, {0.f, 0.f, 0.f, 0.f},
                      {0.f, 0.f, 0.f, 0.f}, {0.f, 0.f, 0.f, 0.f}};
#pragma unroll
  for (int pt = 0; pt < 16; ++pt) {
    const int base = (32 * pt) % 48;  // compile-time: cycles 0,32,16
    // conv1 tiles e=0,1 -> ring rows 32pt+1 .. 32pt+32
#pragma unroll
    for (int e = 0; e < 2; ++e) {
      f32x4 c0 = {0.f, 0.f, 0.f, 0.f}, c1 = {0.f, 0.f, 0.f, 0.f};
#pragma unroll
      for (int s = 0; s < 2; ++s) {
        int row = 32 * pt + 16 * e + a15 + 2 * s + dk0;
        i64 bv = *(const i64*)(xw + row * 16 + icb);
        c0 = mfma8(w1f[0][s], bv, c0);
        c1 = mfma8(w1f[1][s], bv, c1);
      }
      int d = dW[e];
      int slot = base + d;
      if (slot >= 48) slot -= 48;
      int swz = (d >> 2) & 3;
      int off0 = ((((g >> 1) + 0) ^ swz) << 3) | ((g & 1) << 2);
      int off1 = ((((g >> 1) + 2) ^ swz) << 3) | ((g & 1) << 2);
      float v0 = fmaxf(fmaf(c0[0], 0.00390625f, b1v[0][0]), 0.f);
      float v1 = fmaxf(fmaf(c0[1], 0.00390625f, b1v[0][1]), 0.f);
      float v2 = fmaxf(fmaf(c0[2], 0.00390625f, b1v[0][2]), 0.f);
      float v3 = fmaxf(fmaf(c0[3], 0.00390625f, b1v[0][3]), 0.f);
      int pk0 = __builtin_amdgcn_cvt_pk_fp8_f32(v0, v1, 0, false);
      pk0 = __builtin_amdgcn_cvt_pk_fp8_f32(v2, v3, pk0, true);
      *(int*)(ring + slot * 32 + off0) = pk0;
      v0 = fmaxf(fmaf(c1[0], 0.00390625f, b1v[1][0]), 0.f);
      v1 = fmaxf(fmaf(c1[1], 0.00390625f, b1v[1][1]), 0.f);
      v2 = fmaxf(fmaf(c1[2], 0.00390625f, b1v[1][2]), 0.f);
      v3 = fmaxf(fmaf(c1[3], 0.00390625f, b1v[1][3]), 0.f);
      int pk1 = __builtin_amdgcn_cvt_pk_fp8_f32(v0, v1, 0, false);
      pk1 = __builtin_amdgcn_cvt_pk_fp8_f32(v2, v3, pk1, true);
      *(int*)(ring + slot * 32 + off1) = pk1;
    }
    LDS_FENCE();  // conv1 ring writes -> conv2 ring reads (cross-lane)
    // conv2 tile pt: p = pt*16 + a15, rho = 2p+s (ring rows 32pt + 2*a15+s)
    {
      f32x4 cc0 = {0.f, 0.f, 0.f, 0.f}, cc1 = {0.f, 0.f, 0.f, 0.f};
      f32x4 cc2 = {0.f, 0.f, 0.f, 0.f}, cc3 = {0.f, 0.f, 0.f, 0.f};
#pragma unroll
      for (int s = 0; s < 3; ++s) {
        int d = dR0 + s;
        int slot = base + d;
        if (slot >= 48) slot -= 48;
        int swz = (d >> 2) & 3;
        i64 hv = *(const i64*)(ring + slot * 32 + ((g ^ swz) << 3));
        cc0 = mfma8(w2f[0][s], hv, cc0);
        cc1 = mfma8(w2f[1][s], hv, cc1);
        cc2 = mfma8(w2f[2][s], hv, cc2);
        cc3 = mfma8(w2f[3][s], hv, cc3);
      }
#pragma unroll
      for (int r = 0; r < 4; ++r) {
        tacc[0][r] += fmaxf(cc0[r] + b2s[0][r], 0.f);
        tacc[1][r] += fmaxf(cc1[r] + b2s[1][r], 0.f);
        tacc[2][r] += fmaxf(cc2[r] + b2s[2][r], 0.f);
        tacc[3][r] += fmaxf(cc3[r] + b2s[3][r], 0.f);
      }
    }
    LDS_FENCE();  // conv2 reads -> next strip's conv1 writes (ring r == r+48)
  }

  // ---- t_feat: reduce over a15 (= p within tile), write comb[0..63] ----
#pragma unroll
  for (int o = 0; o < 4; ++o)
#pragma unroll
    for (int r = 0; r < 4; ++r) {
      float v = tacc[o][r];
      v += __shfl_xor(v, 1, 16);
      v += __shfl_xor(v, 2, 16);
      v += __shfl_xor(v, 4, 16);
      v += __shfl_xor(v, 8, 16);
      if (a15 == 0) comb[o * 16 + g * 4 + r] = v * (1.f / 4096.f);
    }
  LDS_FENCE();  // comb[0..63] writes -> fusion reads (cross-lane)

  // ---- scores: global f32 A-frags, all 17 k-steps in this wave ----
  const int rcl = (a15 < 12) ? a15 : 11;
  const bf16* MgR = Mg + a15 * MK;
  f32x4 sac = {0.f, 0.f, 0.f, 0.f};
#pragma unroll 4
  for (int s = 0; s < 16; ++s) {
    const float* xs = xb + (s * 32 + g * 8) * 12 + rcl;
    bf16x8 av;
#pragma unroll
    for (int j = 0; j < 8; ++j) av[j] = (bf16)xs[j * 12];
    bf16x8 bm = *(const bf16x8*)&MgR[s * 32 + g * 8];
    sac = mfma16(av, bm, sac);
  }
  {  // k-step 16: slots 512..514 = anchor; rest zero (Mg zero there too)
    bf16x8 av = {(bf16)0.f, (bf16)0.f, (bf16)0.f, (bf16)0.f,
                 (bf16)0.f, (bf16)0.f, (bf16)0.f, (bf16)0.f};
    if (g == 0) {
      av[0] = (bf16)anchor[(size_t)b * 3 + 0];
      av[1] = (bf16)anchor[(size_t)b * 3 + 1];
      av[2] = (bf16)anchor[(size_t)b * 3 + 2];
    }
    bf16x8 bm = *(const bf16x8*)&MgR[512 + g * 8];
    sac = mfma16(av, bm, sac);
  }

  // ---- softmax + s_agg (wave-local; sagg overlays xw, dead after conv1) ----
  float dx = anchor[(size_t)b * 3 + 0] - ledp[a15 * 3 + 0];
  float dy = anchor[(size_t)b * 3 + 1] - ledp[a15 * 3 + 1];
  float dz = anchor[(size_t)b * 3 + 2] - ledp[a15 * 3 + 2];
  float cv = cvec[a15] - 0.5f * __logf(dx * dx + dy * dy + dz * dz + 1e-8f);
  const f32x4* lfp = (const f32x4*)(ledf + a15 * 8);
  f32x4 lfA = lfp[0], lfB = lfp[1];
#pragma unroll
  for (int rho = 0; rho < 4; ++rho) {
    int r = 4 * g + rho;
    int mrow = (r < 12) ? r : 11;
    float s = sac[rho] + cv;
    if (r >= 12 || fmask[mrow * 16 + a15] == 0) s = -FLT_MAX;
    float mx = s;
    mx = fmaxf(mx, __shfl_xor(mx, 1, 16));
    mx = fmaxf(mx, __shfl_xor(mx, 2, 16));
    mx = fmaxf(mx, __shfl_xor(mx, 4, 16));
    mx = fmaxf(mx, __shfl_xor(mx, 8, 16));
    float ev = __expf(s - mx);
    float sm = ev;
    sm += __shfl_xor(sm, 1, 16);
    sm += __shfl_xor(sm, 2, 16);
    sm += __shfl_xor(sm, 4, 16);
    sm += __shfl_xor(sm, 8, 16);
    const float attv = ev / sm;
#pragma unroll
    for (int f = 0; f < 8; ++f) {
      float c = attv * ((f < 4) ? lfA[f] : lfB[f - 4]);
      c += __shfl_xor(c, 1, 16);
      c += __shfl_xor(c, 2, 16);
      c += __shfl_xor(c, 4, 16);
      c += __shfl_xor(c, 8, 16);
      if (a15 == f && r < 12) sagg[r * 8 + f] = c;
    }
  }
  LDS_FENCE();  // sagg writes -> s_feat reads (cross-lane)

  // ---- s_feat: 64 lanes, one output each ----
  {
    float acc = rb[lane];
    const f32x4* rwv = (const f32x4*)(rw + lane * 96);
#pragma unroll
    for (int i = 0; i < 24; ++i) {
      f32x4 a = rwv[i];
      f32x4 sv = *(const f32x4*)&sagg[i * 4];
      acc += a[0] * sv[0] + a[1] * sv[1] + a[2] * sv[2] + a[3] * sv[3];
    }
    comb[64 + lane] = fmaxf(acc, 0.f);
  }
  LDS_FENCE();  // comb[64..127] writes -> fusion reads (cross-lane)

  // ---- fusion: out = fus_w @ comb + fus_b ----
  {
    float acc = fb[lane];
    const f32x4* fwv = (const f32x4*)(fw + lane * 128);
#pragma unroll
    for (int i = 0; i < 32; ++i) {
      f32x4 a = fwv[i];
      f32x4 c = *(const f32x4*)&comb[i * 4];
      acc += a[0] * c[0] + a[1] * c[1] + a[2] * c[2] + a[3] * c[3];
    }
    out[(size_t)b * 64 + lane] = acc;
  }
}

extern "C" void kernel_launch(void* const* d_in, const int* in_sizes, int n_in,
                              void* d_out, int out_size, void* d_ws, size_t ws_size,
                              hipStream_t stream) {
  (void)in_sizes; (void)n_in; (void)out_size; (void)ws_size;
  const float* rss   = (const float*)d_in[0];
  const float* anch  = (const float*)d_in[1];
  const float* ledf  = (const float*)d_in[2];
  const float* ledp  = (const float*)d_in[3];
  const int*   fmask = (const int*)d_in[4];
  const float* c1w = (const float*)d_in[5];
  const float* c1b = (const float*)d_in[6];
  const float* c2w = (const float*)d_in[7];
  const float* c2b = (const float*)d_in[8];
  const float* qw  = (const float*)d_in[9];
  const float* qb  = (const float*)d_in[10];
  const float* kw  = (const float*)d_in[11];
  const float* kb  = (const float*)d_in[12];
  const float* rw  = (const float*)d_in[13];
  const float* rb  = (const float*)d_in[14];
  const float* fw  = (const float*)d_in[15];
  const float* fb  = (const float*)d_in[16];
  float* outp = (float*)d_out;
  char* ws = (char*)d_ws;

  acek_pre<<<35, 256, 0, stream>>>(ledf, ledp, qw, qb, kw, kb, c1w, c2w, ws);
  acek_main<<<2048, 256, 0, stream>>>(
      rss, anch, ledf, ledp, fmask, c1b, c2b, rw, rb, fw, fb,
      (const bf16*)(ws + WS_MG), (const float*)(ws + WS_CVEC),
      (const i64*)(ws + WS_W1F), (const i64*)(ws + WS_W2F), outp);
}

// Round 15
// 129.441 us; speedup vs baseline: 2.6621x; 2.6621x over previous
//
#include <hip/hip_runtime.h>
#include <float.h>
#include <math.h>

typedef __bf16 bf16;
typedef __attribute__((ext_vector_type(8))) __bf16 bf16x8;
typedef __attribute__((ext_vector_type(4))) float f32x4;
typedef long long i64;

#define MK 544  // Mg row stride (bf16); cols [0,515) real, rest zero

// Zero-instruction compiler memory fence: makes cross-lane LDS
// producer->consumer ordering a contract (r13: alias analysis may hoist a
// ds_read above another lane's ds_write when addresses fold to constants).
// In this ROLLED loop the runtime ring base already keeps addresses opaque,
// so these change no schedule — they pin the invariant. (r14: fences + full
// unroll spilled; unroll abandoned.)
#define LDS_FENCE() asm volatile("" ::: "memory")

// workspace byte offsets
#define WS_MG   0        // bf16[16*544]   = 17408 B
#define WS_CVEC 17408    // f32[16]        = 64 B
#define WS_W1F  17472    // i64[2*2*64]    = 2048 B   (fp8 conv1 frags, x16)
#define WS_W2F  19520    // i64[4*3*64]    = 6144 B   (fp8 conv2 frags, x16)

__device__ __forceinline__ f32x4 mfma16(bf16x8 a, bf16x8 b, f32x4 c) {
  return __builtin_amdgcn_mfma_f32_16x16x32_bf16(a, b, c, 0, 0, 0);
}
__device__ __forceinline__ f32x4 mfma8(i64 a, i64 b, f32x4 c) {
  return __builtin_amdgcn_mfma_f32_16x16x32_fp8_fp8(a, b, c, 0, 0, 0);
}

// ---------------------------------------------------------------------------
// Precompute (grid 35): blocks 0..33 build Mg[n][k] (bf16; k<515 real, rest 0)
// and cvec[n]; block 34 builds fp8 weight fragment tables (both scaled x16).
// ---------------------------------------------------------------------------
__global__ __launch_bounds__(256) void acek_pre(
    const float* __restrict__ led_feats, const float* __restrict__ led_pos,
    const float* __restrict__ q_w, const float* __restrict__ q_b,
    const float* __restrict__ k_w, const float* __restrict__ k_b,
    const float* __restrict__ c1w, const float* __restrict__ c2w,
    char* __restrict__ ws) {
  bf16* Mg = (bf16*)(ws + WS_MG);
  float* cvec = (float*)(ws + WS_CVEC);
  i64* W1F = (i64*)(ws + WS_W1F);
  i64* W2F = (i64*)(ws + WS_W2F);
  const int t = threadIdx.x;

  if (blockIdx.x == 34) {
    {  // conv1 fp8 frags: idx (ot*2+s)*64+lane; elem j <-> k1 = s*32+g*8+j
      int ot = t >> 7, s = (t >> 6) & 1, lane = t & 63;
      int g = lane >> 4, a15 = lane & 15;
      float v[8];
#pragma unroll
      for (int j = 0; j < 8; ++j) {
        int k1 = s * 32 + g * 8 + j;
        int dk = k1 >> 4, ic = k1 & 15;
        v[j] = (ic < 12 && dk < 3) ? 16.f * c1w[(ot * 16 + a15) * 36 + ic * 3 + dk] : 0.f;
      }
      int lo = __builtin_amdgcn_cvt_pk_fp8_f32(v[0], v[1], 0, false);
      lo = __builtin_amdgcn_cvt_pk_fp8_f32(v[2], v[3], lo, true);
      int hi = __builtin_amdgcn_cvt_pk_fp8_f32(v[4], v[5], 0, false);
      hi = __builtin_amdgcn_cvt_pk_fp8_f32(v[6], v[7], hi, true);
      W1F[t] = ((i64)(unsigned)lo) | (((i64)hi) << 32);
    }
    for (int r = 0; r < 3; ++r) {  // conv2 fp8 frags
      int fi = t + r * 256;
      int o = fi / 192, rem = fi - o * 192;
      int s = rem >> 6, lane = rem & 63;
      int g = lane >> 4, a15 = lane & 15;
      float v[8];
#pragma unroll
      for (int j = 0; j < 8; ++j)
        v[j] = 16.f * c2w[(o * 16 + a15) * 96 + (g * 8 + j) * 3 + s];
      int lo = __builtin_amdgcn_cvt_pk_fp8_f32(v[0], v[1], 0, false);
      lo = __builtin_amdgcn_cvt_pk_fp8_f32(v[2], v[3], lo, true);
      int hi = __builtin_amdgcn_cvt_pk_fp8_f32(v[4], v[5], 0, false);
      hi = __builtin_amdgcn_cvt_pk_fp8_f32(v[6], v[7], hi, true);
      W2F[fi] = ((i64)(unsigned)lo) | (((i64)hi) << 32);
    }
    return;
  }

  __shared__ float keys[16 * 64];
  for (int idx = t; idx < 16 * 64; idx += 256) {
    int n = idx >> 6, d = idx & 63;
    float acc = k_b[d];
#pragma unroll
    for (int j = 0; j < 8; ++j) acc += k_w[d * 11 + j] * led_feats[n * 8 + j];
#pragma unroll
    for (int j = 0; j < 3; ++j) acc += k_w[d * 11 + 8 + j] * led_pos[n * 3 + j];
    keys[idx] = acc;
  }
  __syncthreads();
  int e = blockIdx.x * 256 + t;
  if (e < 16 * MK) {
    int n = e / MK, k = e - n * MK;
    float v = 0.f;
    if (k < 515) {
#pragma unroll 4
      for (int d = 0; d < 64; ++d) v += q_w[d * 515 + k] * keys[n * 64 + d];
    }
    Mg[e] = (bf16)v;
  }
  if (blockIdx.x == 0 && t < 16) {
    float acc = 0.f;
    for (int d = 0; d < 64; ++d) acc += q_b[d] * keys[t * 64 + d];
    cvec[t] = acc;
  }
}

// ---------------------------------------------------------------------------
// Main: ONE WAVE = ONE BATCH, fully independent; ZERO barriers.
// r9 structure verbatim (130us verified best), ROLLED strip loop (runtime
// ring base), with zero-cost LDS_FENCE pinning every cross-lane LDS
// producer->consumer edge. Terminal kernel of this line: all structural
// levers (barriers, occupancy, interleave, unroll, LDS diet, phase order)
// measured neutral-or-negative vs this structure.
// ---------------------------------------------------------------------------
__global__ __launch_bounds__(256, 4) void acek_main(
    const float* __restrict__ rss, const float* __restrict__ anchor,
    const float* __restrict__ ledf, const float* __restrict__ ledp,
    const int* __restrict__ fmask,
    const float* __restrict__ c1b, const float* __restrict__ c2b,
    const float* __restrict__ rw, const float* __restrict__ rb,
    const float* __restrict__ fw, const float* __restrict__ fb,
    const bf16* __restrict__ Mg, const float* __restrict__ cvec,
    const i64* __restrict__ W1F, const i64* __restrict__ W2F,
    float* __restrict__ out) {

  __shared__ __align__(16) unsigned char pool[4][9792];

  const int tid = threadIdx.x;
  const int lane = tid & 63;
  const int wv = tid >> 6;
  const int a15 = lane & 15;
  const int g = lane >> 4;
  const int b = blockIdx.x * 4 + wv;

  char* xw = (char*)pool[wv];                 // 515 rows x 16 B (fp8 x16)
  char* ring = (char*)pool[wv] + 8240;        // 48 rows x 32 B (h1 fp8)
  float* sagg = (float*)pool[wv];             // 96 f32, overlays dead xw
  float* comb = (float*)(pool[wv] + 8240);    // 128 f32, overlays dead ring

  // ---- fragment/bias loads ----
  i64 w1f[2][2];
#pragma unroll
  for (int ot = 0; ot < 2; ++ot)
#pragma unroll
    for (int s = 0; s < 2; ++s) w1f[ot][s] = W1F[(ot * 2 + s) * 64 + lane];
  i64 w2f[4][3];
#pragma unroll
  for (int o = 0; o < 4; ++o)
#pragma unroll
    for (int s = 0; s < 3; ++s) w2f[o][s] = W2F[(o * 3 + s) * 64 + lane];
  f32x4 b1v[2], b2s[4];
#pragma unroll
  for (int ot = 0; ot < 2; ++ot) b1v[ot] = *(const f32x4*)&c1b[ot * 16 + g * 4];
#pragma unroll
  for (int o = 0; o < 4; ++o) {
    f32x4 tmp = *(const f32x4*)&c2b[o * 16 + g * 4];
    b2s[o] = tmp * 16.f;  // conv2 fp8 weight scale folded into bias
  }

  // ---- zero pads (own wave's LDS only) ----
  for (int r = lane; r < 515; r += 64) *(int*)(xw + r * 16 + 12) = 0;  // cols 12-15
  if (lane < 12) {  // xw rows 0, 513, 514 (cols 0-15)
    int rr = (lane >> 2) == 0 ? 0 : ((lane >> 2) == 1 ? 513 : 514);
    *(int*)(xw + rr * 16 + (lane & 3) * 4) = 0;
  }
  if (lane < 4) *(i64*)(ring + lane * 8) = 0;  // ring slot 0 = h1 row 0 (zero pad)

  // ---- stage own batch: 24 coalesced f32x4 per lane -> fp8 (x16) LDS ----
  const float* xb = rss + (size_t)b * 6144;
  const f32x4* xb4 = (const f32x4*)xb;
#pragma unroll
  for (int i = 0; i < 24; ++i) {
    int f = lane + 64 * i;
    f32x4 v = xb4[f];
    int w = f / 3;
    int c = f - w * 3;  // {0,1,2}
    int pk = __builtin_amdgcn_cvt_pk_fp8_f32(16.f * v[0], 16.f * v[1], 0, false);
    pk = __builtin_amdgcn_cvt_pk_fp8_f32(16.f * v[2], 16.f * v[3], pk, true);
    *(int*)(xw + (w + 1) * 16 + c * 4) = pk;
  }
  LDS_FENCE();  // staging/pads -> conv1 reads (cross-lane)

  // ---- fused conv1 -> ring -> conv2, 16 strips of 32 outputs (ROLLED) ----
  const int icb = (g & 1) << 3;  // xw byte sub-block
  const int dk0 = g >> 1;
  const int dW[2] = {a15 + 1, a15 + 17};  // conv1-write d = row - 32pt
  const int dR0 = 2 * a15;                // conv2-read base d

  float tacc[4][4] = {{0.f, 0.f, 0.f, 0.f}, {0.f, 0.f, 0.f, 0.f},
                      {0.f, 0.f, 0.f, 0.f}, {0.f, 0.f, 0.f, 0.f}};
  int base = 0;  // (32*pt) mod 48, cycles 0,32,16
  for (int pt = 0; pt < 16; ++pt) {
    // conv1 tiles e=0,1 -> ring rows 32pt+1 .. 32pt+32
#pragma unroll
    for (int e = 0; e < 2; ++e) {
      f32x4 c0 = {0.f, 0.f, 0.f, 0.f}, c1 = {0.f, 0.f, 0.f, 0.f};
#pragma unroll
      for (int s = 0; s < 2; ++s) {
        int row = 32 * pt + 16 * e + a15 + 2 * s + dk0;
        i64 bv = *(const i64*)(xw + row * 16 + icb);
        c0 = mfma8(w1f[0][s], bv, c0);
        c1 = mfma8(w1f[1][s], bv, c1);
      }
      int d = dW[e];
      int slot = base + d;
      if (slot >= 48) slot -= 48;
      int swz = (d >> 2) & 3;
      int off0 = ((((g >> 1) + 0) ^ swz) << 3) | ((g & 1) << 2);
      int off1 = ((((g >> 1) + 2) ^ swz) << 3) | ((g & 1) << 2);
      float v0 = fmaxf(fmaf(c0[0], 0.00390625f, b1v[0][0]), 0.f);
      float v1 = fmaxf(fmaf(c0[1], 0.00390625f, b1v[0][1]), 0.f);
      float v2 = fmaxf(fmaf(c0[2], 0.00390625f, b1v[0][2]), 0.f);
      float v3 = fmaxf(fmaf(c0[3], 0.00390625f, b1v[0][3]), 0.f);
      int pk0 = __builtin_amdgcn_cvt_pk_fp8_f32(v0, v1, 0, false);
      pk0 = __builtin_amdgcn_cvt_pk_fp8_f32(v2, v3, pk0, true);
      *(int*)(ring + slot * 32 + off0) = pk0;
      v0 = fmaxf(fmaf(c1[0], 0.00390625f, b1v[1][0]), 0.f);
      v1 = fmaxf(fmaf(c1[1], 0.00390625f, b1v[1][1]), 0.f);
      v2 = fmaxf(fmaf(c1[2], 0.00390625f, b1v[1][2]), 0.f);
      v3 = fmaxf(fmaf(c1[3], 0.00390625f, b1v[1][3]), 0.f);
      int pk1 = __builtin_amdgcn_cvt_pk_fp8_f32(v0, v1, 0, false);
      pk1 = __builtin_amdgcn_cvt_pk_fp8_f32(v2, v3, pk1, true);
      *(int*)(ring + slot * 32 + off1) = pk1;
    }
    LDS_FENCE();  // conv1 ring writes -> conv2 ring reads (cross-lane)
    // conv2 tile pt: p = pt*16 + a15, rho = 2p+s (ring rows 32pt + 2*a15+s)
    {
      f32x4 cc0 = {0.f, 0.f, 0.f, 0.f}, cc1 = {0.f, 0.f, 0.f, 0.f};
      f32x4 cc2 = {0.f, 0.f, 0.f, 0.f}, cc3 = {0.f, 0.f, 0.f, 0.f};
#pragma unroll
      for (int s = 0; s < 3; ++s) {
        int d = dR0 + s;
        int slot = base + d;
        if (slot >= 48) slot -= 48;
        int swz = (d >> 2) & 3;
        i64 hv = *(const i64*)(ring + slot * 32 + ((g ^ swz) << 3));
        cc0 = mfma8(w2f[0][s], hv, cc0);
        cc1 = mfma8(w2f[1][s], hv, cc1);
        cc2 = mfma8(w2f[2][s], hv, cc2);
        cc3 = mfma8(w2f[3][s], hv, cc3);
      }
#pragma unroll
      for (int r = 0; r < 4; ++r) {
        tacc[0][r] += fmaxf(cc0[r] + b2s[0][r], 0.f);
        tacc[1][r] += fmaxf(cc1[r] + b2s[1][r], 0.f);
        tacc[2][r] += fmaxf(cc2[r] + b2s[2][r], 0.f);
        tacc[3][r] += fmaxf(cc3[r] + b2s[3][r], 0.f);
      }
    }
    LDS_FENCE();  // conv2 reads -> next strip's conv1 writes (ring aliasing)
    base += 32;
    if (base >= 48) base -= 48;
  }

  // ---- t_feat: reduce over a15 (= p within tile), write comb[0..63] ----
#pragma unroll
  for (int o = 0; o < 4; ++o)
#pragma unroll
    for (int r = 0; r < 4; ++r) {
      float v = tacc[o][r];
      v += __shfl_xor(v, 1, 16);
      v += __shfl_xor(v, 2, 16);
      v += __shfl_xor(v, 4, 16);
      v += __shfl_xor(v, 8, 16);
      if (a15 == 0) comb[o * 16 + g * 4 + r] = v * (1.f / 4096.f);
    }
  LDS_FENCE();  // comb[0..63] writes -> fusion reads (cross-lane)

  // ---- scores: global f32 A-frags, all 17 k-steps in this wave ----
  const int rcl = (a15 < 12) ? a15 : 11;
  const bf16* MgR = Mg + a15 * MK;
  f32x4 sac = {0.f, 0.f, 0.f, 0.f};
#pragma unroll 4
  for (int s = 0; s < 16; ++s) {
    const float* xs = xb + (s * 32 + g * 8) * 12 + rcl;
    bf16x8 av;
#pragma unroll
    for (int j = 0; j < 8; ++j) av[j] = (bf16)xs[j * 12];
    bf16x8 bm = *(const bf16x8*)&MgR[s * 32 + g * 8];
    sac = mfma16(av, bm, sac);
  }
  {  // k-step 16: slots 512..514 = anchor; rest zero (Mg zero there too)
    bf16x8 av = {(bf16)0.f, (bf16)0.f, (bf16)0.f, (bf16)0.f,
                 (bf16)0.f, (bf16)0.f, (bf16)0.f, (bf16)0.f};
    if (g == 0) {
      av[0] = (bf16)anchor[(size_t)b * 3 + 0];
      av[1] = (bf16)anchor[(size_t)b * 3 + 1];
      av[2] = (bf16)anchor[(size_t)b * 3 + 2];
    }
    bf16x8 bm = *(const bf16x8*)&MgR[512 + g * 8];
    sac = mfma16(av, bm, sac);
  }

  // ---- softmax + s_agg (wave-local; sagg overlays xw, dead after conv1) ----
  float dx = anchor[(size_t)b * 3 + 0] - ledp[a15 * 3 + 0];
  float dy = anchor[(size_t)b * 3 + 1] - ledp[a15 * 3 + 1];
  float dz = anchor[(size_t)b * 3 + 2] - ledp[a15 * 3 + 2];
  float cv = cvec[a15] - 0.5f * __logf(dx * dx + dy * dy + dz * dz + 1e-8f);
  const f32x4* lfp = (const f32x4*)(ledf + a15 * 8);
  f32x4 lfA = lfp[0], lfB = lfp[1];
#pragma unroll
  for (int rho = 0; rho < 4; ++rho) {
    int r = 4 * g + rho;
    int mrow = (r < 12) ? r : 11;
    float s = sac[rho] + cv;
    if (r >= 12 || fmask[mrow * 16 + a15] == 0) s = -FLT_MAX;
    float mx = s;
    mx = fmaxf(mx, __shfl_xor(mx, 1, 16));
    mx = fmaxf(mx, __shfl_xor(mx, 2, 16));
    mx = fmaxf(mx, __shfl_xor(mx, 4, 16));
    mx = fmaxf(mx, __shfl_xor(mx, 8, 16));
    float ev = __expf(s - mx);
    float sm = ev;
    sm += __shfl_xor(sm, 1, 16);
    sm += __shfl_xor(sm, 2, 16);
    sm += __shfl_xor(sm, 4, 16);
    sm += __shfl_xor(sm, 8, 16);
    const float attv = ev / sm;
#pragma unroll
    for (int f = 0; f < 8; ++f) {
      float c = attv * ((f < 4) ? lfA[f] : lfB[f - 4]);
      c += __shfl_xor(c, 1, 16);
      c += __shfl_xor(c, 2, 16);
      c += __shfl_xor(c, 4, 16);
      c += __shfl_xor(c, 8, 16);
      if (a15 == f && r < 12) sagg[r * 8 + f] = c;
    }
  }
  LDS_FENCE();  // sagg writes -> s_feat reads (cross-lane)

  // ---- s_feat: 64 lanes, one output each ----
  {
    float acc = rb[lane];
    const f32x4* rwv = (const f32x4*)(rw + lane * 96);
#pragma unroll
    for (int i = 0; i < 24; ++i) {
      f32x4 a = rwv[i];
      f32x4 sv = *(const f32x4*)&sagg[i * 4];
      acc += a[0] * sv[0] + a[1] * sv[1] + a[2] * sv[2] + a[3] * sv[3];
    }
    comb[64 + lane] = fmaxf(acc, 0.f);
  }
  LDS_FENCE();  // comb[64..127] writes -> fusion reads (cross-lane)

  // ---- fusion: out = fus_w @ comb + fus_b ----
  {
    float acc = fb[lane];
    const f32x4* fwv = (const f32x4*)(fw + lane * 128);
#pragma unroll
    for (int i = 0; i < 32; ++i) {
      f32x4 a = fwv[i];
      f32x4 c = *(const f32x4*)&comb[i * 4];
      acc += a[0] * c[0] + a[1] * c[1] + a[2] * c[2] + a[3] * c[3];
    }
    out[(size_t)b * 64 + lane] = acc;
  }
}

extern "C" void kernel_launch(void* const* d_in, const int* in_sizes, int n_in,
                              void* d_out, int out_size, void* d_ws, size_t ws_size,
                              hipStream_t stream) {
  (void)in_sizes; (void)n_in; (void)out_size; (void)ws_size;
  const float* rss   = (const float*)d_in[0];
  const float* anch  = (const float*)d_in[1];
  const float* ledf  = (const float*)d_in[2];
  const float* ledp  = (const float*)d_in[3];
  const int*   fmask = (const int*)d_in[4];
  const float* c1w = (const float*)d_in[5];
  const float* c1b = (const float*)d_in[6];
  const float* c2w = (const float*)d_in[7];
  const float* c2b = (const float*)d_in[8];
  const float* qw  = (const float*)d_in[9];
  const float* qb  = (const float*)d_in[10];
  const float* kw  = (const float*)d_in[11];
  const float* kb  = (const float*)d_in[12];
  const float* rw  = (const float*)d_in[13];
  const float* rb  = (const float*)d_in[14];
  const float* fw  = (const float*)d_in[15];
  const float* fb  = (const float*)d_in[16];
  float* outp = (float*)d_out;
  char* ws = (char*)d_ws;

  acek_pre<<<35, 256, 0, stream>>>(ledf, ledp, qw, qb, kw, kb, c1w, c2w, ws);
  acek_main<<<2048, 256, 0, stream>>>(
      rss, anch, ledf, ledp, fmask, c1b, c2b, rw, rb, fw, fb,
      (const bf16*)(ws + WS_MG), (const float*)(ws + WS_CVEC),
      (const i64*)(ws + WS_W1F), (const i64*)(ws + WS_W2F), outp);
}